// Round 1
// baseline (4243.027 us; speedup 1.0000x reference)
//
#include <hip/hip_runtime.h>
#include <math.h>

// Shapes (fixed by setup_inputs)
#define BATCH 8
#define TSEQ 2048
#define CIN 3
#define WIN 5
#define LSEQ 2044          // T - WIN + 1
#define LH 2045            // LSEQ + 1 (cls token appended)
#define DIM 128
#define DEPTH 4
#define DIN 256            // d_inner
#define NH 4               // heads
#define PDIM 64            // headdim
#define NSTATE 64          // d_state
#define CONVD 384          // d_inner + 2*d_state
#define DPROJ 644          // 2*d_inner + 2*d_state + nheads
#define NSPLIT 4           // n-dimension split of the scan
#define NSL 16             // NSTATE / NSPLIT

__device__ __forceinline__ float sigmoidf_(float x){ return 1.f/(1.f+__expf(-x)); }
__device__ __forceinline__ float siluf_(float x){ return x*sigmoidf_(x); }

// ---------------------------------------------------------------- front MLP
// grid: BATCH*LH, block: 128
__global__ void k_front(const float* __restrict__ x, const float* __restrict__ w1,
                        const float* __restrict__ b1, const float* __restrict__ w2,
                        const float* __restrict__ b2, const float* __restrict__ cls,
                        float* __restrict__ h) {
  int blk = blockIdx.x;
  int b = blk / LH, l = blk % LH;
  int t = threadIdx.x;
  if (l == LSEQ) { h[((size_t)b*LH + l)*DIM + t] = cls[t]; return; }
  __shared__ float tok[WIN*CIN];
  __shared__ float h1[DIM];
  if (t < WIN*CIN) tok[t] = x[(size_t)b*TSEQ*CIN + (size_t)l*CIN + t];
  __syncthreads();
  float a = b1[t];
  const float* w1r = w1 + t*(WIN*CIN);
#pragma unroll
  for (int k = 0; k < WIN*CIN; ++k) a += tok[k]*w1r[k];
  float g = 0.5f*a*(1.f + erff(a*0.70710678118654752f));   // exact gelu
  h1[t] = g;
  __syncthreads();
  float o = b2[t];
  const float* w2r = w2 + t*DIM;
  for (int k = 0; k < DIM; ++k) o += h1[k]*w2r[k];
  h[((size_t)b*LH + l)*DIM + t] = o;
}

// ---------------------------------------------------------------- in_proj (+ dt softplus)
// grid: BATCH * 128 (l-tiles of 16), block: 256
#define TR2 16
__global__ void k_inproj(const float* __restrict__ h, const float* __restrict__ w,
                         const float* __restrict__ dtb, float* __restrict__ zx) {
  const int nblk_l = (LH + TR2 - 1) / TR2;   // 128
  int b = blockIdx.x / nblk_l;
  int l0 = (blockIdx.x % nblk_l) * TR2;
  int t = threadIdx.x;
  __shared__ float hs[TR2][DIM];
  for (int i = t; i < TR2*DIM; i += 256) {
    int r = i / DIM, k = i % DIM;
    int l = l0 + r;
    hs[r][k] = (l < LH) ? h[((size_t)b*LH + l)*DIM + k] : 0.f;
  }
  __syncthreads();
  for (int j = t; j < DPROJ; j += 256) {
    float acc[TR2];
#pragma unroll
    for (int r = 0; r < TR2; ++r) acc[r] = 0.f;
    const float* wr = w + (size_t)j*DIM;
    for (int k = 0; k < DIM; ++k) {
      float wv = wr[k];
#pragma unroll
      for (int r = 0; r < TR2; ++r) acc[r] += wv * hs[r][k];
    }
    bool isdt = (j >= 2*DIN + 2*NSTATE);      // j >= 640
    float bias = 0.f;
    if (isdt) bias = dtb[j - 640];
    for (int r = 0; r < TR2; ++r) {
      int l = l0 + r;
      if (l >= LH) break;
      float v = acc[r];
      if (isdt) { v += bias; v = (v > 20.f) ? v : log1pf(__expf(v)); } // softplus
      zx[((size_t)b*LH + l)*DPROJ + j] = v;
    }
  }
}

// ---------------------------------------------------------------- causal dwconv + silu
__global__ void k_conv(const float* __restrict__ zx, const float* __restrict__ cw,
                       const float* __restrict__ cb, float* __restrict__ xbc) {
  size_t idx = (size_t)blockIdx.x*blockDim.x + threadIdx.x;
  const size_t total = (size_t)BATCH*LH*CONVD;
  if (idx >= total) return;
  int c = (int)(idx % CONVD);
  size_t bl = idx / CONVD;
  int l = (int)(bl % LH); int b = (int)(bl / LH);
  float acc = cb[c];
#pragma unroll
  for (int k = 0; k < 4; ++k) {
    int tin = l - 3 + k;
    if (tin >= 0) acc += zx[((size_t)b*LH + tin)*DPROJ + DIN + c] * cw[c*4 + k];
  }
  xbc[idx] = siluf_(acc);
}

// ---------------------------------------------------------------- sequential SSM scan
// grid: BATCH*NH*NSPLIT = 128, block: 64 (one wave; lane = p)
__global__ void __launch_bounds__(64) k_scan(const float* __restrict__ zx,
                       const float* __restrict__ xbc, const float* __restrict__ A_log,
                       float* __restrict__ y) {
  int blk = blockIdx.x;
  int s  = blk & 3;
  int hd = (blk >> 2) & 3;
  int b  = blk >> 4;
  int lane = threadIdx.x;
  float A = -__expf(A_log[hd]);
  float st[NSL];
#pragma unroll
  for (int i = 0; i < NSL; ++i) st[i] = 0.f;
  const float* dtp = zx  + (size_t)b*LH*DPROJ + 640 + hd;
  const float* xp  = xbc + (size_t)b*LH*CONVD + hd*PDIM + lane;
  const float* bp  = xbc + (size_t)b*LH*CONVD + DIN + s*NSL;   // B slice
  const float* cp  = bp + NSTATE;                               // C slice
  float* yp = y + (size_t)b*LH*DIN + hd*PDIM + lane;
  // software pipeline: preload t=0
  float dt = dtp[0], xv = xp[0];
  float Bc[NSL], Cc[NSL];
#pragma unroll
  for (int i = 0; i < NSL; ++i) { Bc[i] = bp[i]; Cc[i] = cp[i]; }
  for (int t = 0; t < LH; ++t) {
    float dtn = 0.f, xvn = 0.f, Bn[NSL], Cn[NSL];
    if (t + 1 < LH) {
      size_t oz = (size_t)(t+1)*DPROJ, ox = (size_t)(t+1)*CONVD;
      dtn = dtp[oz]; xvn = xp[ox];
#pragma unroll
      for (int i = 0; i < NSL; ++i) { Bn[i] = bp[ox+i]; Cn[i] = cp[ox+i]; }
    } else {
#pragma unroll
      for (int i = 0; i < NSL; ++i) { Bn[i] = 0.f; Cn[i] = 0.f; }
    }
    float decay = __expf(dt * A);
    float coef  = dt * xv;
    float acc = 0.f;
#pragma unroll
    for (int i = 0; i < NSL; ++i) {
      st[i] = st[i]*decay + coef*Bc[i];
      acc  += st[i]*Cc[i];
    }
    atomicAdd(yp + (size_t)t*DIN, acc);
    dt = dtn; xv = xvn;
#pragma unroll
    for (int i = 0; i < NSL; ++i) { Bc[i] = Bn[i]; Cc[i] = Cn[i]; }
  }
}

// ---------------------------------------------------------------- gate + rmsnorm + out_proj
// grid: BATCH * 256 (l-tiles of 8), block: 256
#define TR5 8
__global__ void k_out(const float* __restrict__ y, const float* __restrict__ xbc,
                      const float* __restrict__ zx, const float* __restrict__ Dh,
                      const float* __restrict__ nw, const float* __restrict__ ow,
                      float* __restrict__ h) {
  const int nblk_l = (LH + TR5 - 1) / TR5;    // 256
  int b = blockIdx.x / nblk_l;
  int l0 = (blockIdx.x % nblk_l) * TR5;
  int t = threadIdx.x;
  __shared__ float yv[TR5][DIN];
  __shared__ float red[TR5][4];
  __shared__ float rs[TR5];
  int c = t;
  int hd = c >> 6;
  float dcoef = Dh[hd];
  float nwc = nw[c];
  float v[TR5];
#pragma unroll
  for (int r = 0; r < TR5; ++r) {
    int l = l0 + r;
    float val = 0.f;
    if (l < LH) {
      size_t row = (size_t)b*LH + l;
      float ys = y[row*DIN + c];
      float xh = xbc[row*CONVD + c];
      float z  = zx[row*DPROJ + c];
      val = (ys + dcoef*xh) * siluf_(z);
    }
    v[r] = val;
  }
  int wave = t >> 6, lane = t & 63;
#pragma unroll
  for (int r = 0; r < TR5; ++r) {
    float sq = v[r]*v[r];
    for (int off = 32; off > 0; off >>= 1) sq += __shfl_down(sq, off);
    if (lane == 0) red[r][wave] = sq;
  }
  __syncthreads();
  if (t < TR5) {
    float sm = red[t][0]+red[t][1]+red[t][2]+red[t][3];
    rs[t] = rsqrtf(sm/(float)DIN + 1e-5f);
  }
  __syncthreads();
#pragma unroll
  for (int r = 0; r < TR5; ++r) yv[r][c] = v[r] * rs[r] * nwc;
  __syncthreads();
  // matmul: j = t&127, k-half = t>>7
  int j = t & 127, hf = t >> 7;
  float acc[TR5];
#pragma unroll
  for (int r = 0; r < TR5; ++r) acc[r] = 0.f;
  const float* wr = ow + (size_t)j*DIN + hf*128;
  for (int k = 0; k < 128; ++k) {
    float wv = wr[k];
#pragma unroll
    for (int r = 0; r < TR5; ++r) acc[r] += wv * yv[r][hf*128 + k];
  }
  __syncthreads();
#pragma unroll
  for (int r = 0; r < TR5; ++r) yv[r][hf*128 + j] = acc[r];   // yv[r][t] = partial
  __syncthreads();
  if (hf == 0) {
#pragma unroll
    for (int r = 0; r < TR5; ++r) {
      int l = l0 + r;
      if (l < LH) h[((size_t)b*LH + l)*DIM + j] = yv[r][j] + yv[r][128 + j];
    }
  }
}

// ---------------------------------------------------------------- final LN + head
// grid: BATCH, block: 128
__global__ void k_head(const float* __restrict__ h, const float* __restrict__ lnw,
                       const float* __restrict__ lnb, const float* __restrict__ hw,
                       const float* __restrict__ hb, float* __restrict__ out) {
  int b = blockIdx.x; int t = threadIdx.x;
  __shared__ float red[2];
  int wave = t >> 6, lane = t & 63;
  float v = h[((size_t)b*LH + LSEQ)*DIM + t];
  float s = v;
  for (int off = 32; off > 0; off >>= 1) s += __shfl_down(s, off);
  if (lane == 0) red[wave] = s;
  __syncthreads();
  float mean = (red[0]+red[1]) / (float)DIM;
  __syncthreads();
  float d = v - mean; float sq = d*d;
  for (int off = 32; off > 0; off >>= 1) sq += __shfl_down(sq, off);
  if (lane == 0) red[wave] = sq;
  __syncthreads();
  float var = (red[0]+red[1]) / (float)DIM;
  float cn = d*rsqrtf(var + 1e-5f)*lnw[t] + lnb[t];
  float dot = cn*hw[t];
  __syncthreads();
  for (int off = 32; off > 0; off >>= 1) dot += __shfl_down(dot, off);
  if (lane == 0) red[wave] = dot;
  __syncthreads();
  if (t == 0) out[b] = red[0]+red[1] + hb[0];
}

// ---------------------------------------------------------------- h -> d_out copy
__global__ void k_copy(const float* __restrict__ src, float* __restrict__ dst, long n4) {
  long i = (long)blockIdx.x*blockDim.x + threadIdx.x;
  if (i < n4) ((float4*)dst)[i] = ((const float4*)src)[i];
}

extern "C" void kernel_launch(void* const* d_in, const int* in_sizes, int n_in,
                              void* d_out, int out_size, void* d_ws, size_t ws_size,
                              hipStream_t stream) {
  const float* x     = (const float*)d_in[0];
  const float* w1    = (const float*)d_in[1];
  const float* b1    = (const float*)d_in[2];
  const float* w2    = (const float*)d_in[3];
  const float* b2    = (const float*)d_in[4];
  const float* cls   = (const float*)d_in[5];
  const float* inw   = (const float*)d_in[6];   // (4, 644, 128)
  const float* cw    = (const float*)d_in[7];   // (4, 384, 4)
  const float* cb    = (const float*)d_in[8];   // (4, 384)
  const float* dtb   = (const float*)d_in[9];   // (4, 4)
  const float* Alog  = (const float*)d_in[10];  // (4, 4)
  const float* Dh    = (const float*)d_in[11];  // (4, 4)
  const float* nw    = (const float*)d_in[12];  // (4, 256)
  const float* ow    = (const float*)d_in[13];  // (4, 128, 256)
  const float* lnw   = (const float*)d_in[14];
  const float* lnb   = (const float*)d_in[15];
  const float* hw    = (const float*)d_in[16];
  const float* hb    = (const float*)d_in[17];

  float* ws   = (float*)d_ws;
  float* hbuf = ws;                                   // 8*2045*128  = 2,094,080
  float* zx   = hbuf + (size_t)BATCH*LH*DIM;          // 8*2045*644  = 10,535,840
  float* xbc  = zx   + (size_t)BATCH*LH*DPROJ;        // 8*2045*384  = 6,282,240
  float* ybuf = xbc  + (size_t)BATCH*LH*CONVD;        // 8*2045*256  = 4,188,160
  // total ws use: 23,100,320 floats = 92.4 MB

  k_front<<<BATCH*LH, 128, 0, stream>>>(x, w1, b1, w2, b2, cls, hbuf);

  for (int i = 0; i < DEPTH; ++i) {
    k_inproj<<<BATCH*((LH+TR2-1)/TR2), 256, 0, stream>>>(
        hbuf, inw + (size_t)i*DPROJ*DIM, dtb + i*NH, zx);
    {
      long total = (long)BATCH*LH*CONVD;
      k_conv<<<(int)((total + 255)/256), 256, 0, stream>>>(
          zx, cw + (size_t)i*CONVD*4, cb + (size_t)i*CONVD, xbc);
    }
    hipMemsetAsync(ybuf, 0, (size_t)BATCH*LH*DIN*sizeof(float), stream);
    k_scan<<<BATCH*NH*NSPLIT, 64, 0, stream>>>(zx, xbc, Alog + i*NH, ybuf);
    k_out<<<BATCH*((LH+TR5-1)/TR5), 256, 0, stream>>>(
        ybuf, xbc, zx, Dh + i*NH, nw + (size_t)i*DIN, ow + (size_t)i*DIM*DIN, hbuf);
  }

  k_head<<<BATCH, 128, 0, stream>>>(hbuf, lnw, lnb, hw, hb, (float*)d_out);
  {
    long n4 = (long)BATCH*LH*DIM/4;   // 523,520 float4s
    k_copy<<<(int)((n4 + 255)/256), 256, 0, stream>>>(hbuf, (float*)d_out + 8, n4);
  }
}

// Round 2
// 2303.462 us; speedup vs baseline: 1.8420x; 1.8420x over previous
//
#include <hip/hip_runtime.h>
#include <math.h>

// Shapes (fixed by setup_inputs)
#define BATCH 8
#define TSEQ 2048
#define CIN 3
#define WIN 5
#define LSEQ 2044          // T - WIN + 1
#define LH 2045            // LSEQ + 1 (cls token appended)
#define DIM 128
#define DEPTH 4
#define DIN 256            // d_inner
#define NH 4               // heads
#define PDIM 64            // headdim
#define NSTATE 64          // d_state
#define CONVD 384          // d_inner + 2*d_state
#define DPROJ 644          // 2*d_inner + 2*d_state + nheads
#define QC 64              // chunk length
#define NCH 32             // number of chunks (32*64 = 2048 >= 2045)
#define LDP 68             // padded LDS row stride (17 float4s; bank-spread)

__device__ __forceinline__ float sigmoidf_(float x){ return 1.f/(1.f+__expf(-x)); }
__device__ __forceinline__ float siluf_(float x){ return x*sigmoidf_(x); }

// ---------------------------------------------------------------- front MLP
__global__ void k_front(const float* __restrict__ x, const float* __restrict__ w1,
                        const float* __restrict__ b1, const float* __restrict__ w2,
                        const float* __restrict__ b2, const float* __restrict__ cls,
                        float* __restrict__ h) {
  int blk = blockIdx.x;
  int b = blk / LH, l = blk % LH;
  int t = threadIdx.x;
  if (l == LSEQ) { h[((size_t)b*LH + l)*DIM + t] = cls[t]; return; }
  __shared__ float tok[WIN*CIN];
  __shared__ float h1[DIM];
  if (t < WIN*CIN) tok[t] = x[(size_t)b*TSEQ*CIN + (size_t)l*CIN + t];
  __syncthreads();
  float a = b1[t];
  const float* w1r = w1 + t*(WIN*CIN);
#pragma unroll
  for (int k = 0; k < WIN*CIN; ++k) a += tok[k]*w1r[k];
  float g = 0.5f*a*(1.f + erff(a*0.70710678118654752f));   // exact gelu
  h1[t] = g;
  __syncthreads();
  float o = b2[t];
  const float* w2r = w2 + t*DIM;
  for (int k = 0; k < DIM; ++k) o += h1[k]*w2r[k];
  h[((size_t)b*LH + l)*DIM + t] = o;
}

// ---------------------------------------------------------------- in_proj (+ dt softplus)
#define TR2 16
__global__ void k_inproj(const float* __restrict__ h, const float* __restrict__ w,
                         const float* __restrict__ dtb, float* __restrict__ zx) {
  const int nblk_l = (LH + TR2 - 1) / TR2;   // 128
  int b = blockIdx.x / nblk_l;
  int l0 = (blockIdx.x % nblk_l) * TR2;
  int t = threadIdx.x;
  __shared__ float hs[TR2][DIM];
  for (int i = t; i < TR2*DIM; i += 256) {
    int r = i / DIM, k = i % DIM;
    int l = l0 + r;
    hs[r][k] = (l < LH) ? h[((size_t)b*LH + l)*DIM + k] : 0.f;
  }
  __syncthreads();
  for (int j = t; j < DPROJ; j += 256) {
    float acc[TR2];
#pragma unroll
    for (int r = 0; r < TR2; ++r) acc[r] = 0.f;
    const float* wr = w + (size_t)j*DIM;
    for (int k = 0; k < DIM; ++k) {
      float wv = wr[k];
#pragma unroll
      for (int r = 0; r < TR2; ++r) acc[r] += wv * hs[r][k];
    }
    bool isdt = (j >= 2*DIN + 2*NSTATE);      // j >= 640
    float bias = 0.f;
    if (isdt) bias = dtb[j - 640];
    for (int r = 0; r < TR2; ++r) {
      int l = l0 + r;
      if (l >= LH) break;
      float v = acc[r];
      if (isdt) { v += bias; v = (v > 20.f) ? v : log1pf(__expf(v)); } // softplus
      zx[((size_t)b*LH + l)*DPROJ + j] = v;
    }
  }
}

// ---------------------------------------------------------------- causal dwconv + silu
__global__ void k_conv(const float* __restrict__ zx, const float* __restrict__ cw,
                       const float* __restrict__ cb, float* __restrict__ xbc) {
  size_t idx = (size_t)blockIdx.x*blockDim.x + threadIdx.x;
  const size_t total = (size_t)BATCH*LH*CONVD;
  if (idx >= total) return;
  int c = (int)(idx % CONVD);
  size_t bl = idx / CONVD;
  int l = (int)(bl % LH); int b = (int)(bl / LH);
  float acc = cb[c];
#pragma unroll
  for (int k = 0; k < 4; ++k) {
    int tin = l - 3 + k;
    if (tin >= 0) acc += zx[((size_t)b*LH + tin)*DPROJ + DIN + c] * cw[c*4 + k];
  }
  xbc[idx] = siluf_(acc);
}

// ---------------------------------------------------------------- chunked SSD, phase A:
// per-chunk local state G (stored transposed: flat[n*64+p] = H_local[p][n]) + chunk decay
// grid: BATCH*NH*NCH = 1024, block 256
__global__ void __launch_bounds__(256) k_chunk_state(
    const float* __restrict__ zx, const float* __restrict__ xbc,
    const float* __restrict__ A_log, float* __restrict__ G, float* __restrict__ dec) {
  int blk = blockIdx.x;
  int c = blk & (NCH-1), hd = (blk >> 5) & 3, b = blk >> 7;
  int t0 = c*QC;
  int tid = threadIdx.x;
  float A = -__expf(A_log[hd]);
  __shared__ float xs[QC*PDIM];     // [s][p]
  __shared__ float Bs[QC*NSTATE];   // [s][n]
  __shared__ float coef[QC];
  if (tid < 64) {
    int tg = t0 + tid;
    float dtv = (tg < LH) ? zx[((size_t)b*LH + tg)*DPROJ + 640 + hd] : 0.f;
    float s = dtv;
#pragma unroll
    for (int off = 1; off < 64; off <<= 1) {
      float u = __shfl_up(s, off);
      if (tid >= off) s += u;
    }
    float cq = __shfl(s, 63);
    coef[tid] = __expf(A*(cq - s)) * dtv;
    if (tid == 63) dec[blk] = __expf(A * s);
  }
  for (int i = tid; i < QC*64; i += 256) {
    int s = i >> 6, j = i & 63;
    int tg = t0 + s;
    float xv = 0.f, bv = 0.f;
    if (tg < LH) {
      size_t row = ((size_t)b*LH + tg)*CONVD;
      xv = xbc[row + hd*PDIM + j];
      bv = xbc[row + DIN + j];
    }
    xs[i] = xv; Bs[i] = bv;
  }
  __syncthreads();
  int n = tid >> 2, q = tid & 3;            // thread owns (n, p in [q*16, q*16+16))
  float4 acc[4];
#pragma unroll
  for (int i4 = 0; i4 < 4; ++i4) acc[i4] = make_float4(0.f,0.f,0.f,0.f);
  const float4* xs4 = (const float4*)xs;
  for (int s = 0; s < QC; ++s) {
    float cb_ = coef[s] * Bs[s*64 + n];
#pragma unroll
    for (int i4 = 0; i4 < 4; ++i4) {
      float4 xv = xs4[s*16 + q*4 + i4];
      acc[i4].x += cb_*xv.x; acc[i4].y += cb_*xv.y;
      acc[i4].z += cb_*xv.z; acc[i4].w += cb_*xv.w;
    }
  }
  float4* gp = (float4*)(G + (size_t)blk*4096 + n*64 + q*16);
#pragma unroll
  for (int i4 = 0; i4 < 4; ++i4) gp[i4] = acc[i4];
}

// ---------------------------------------------------------------- phase B: inter-chunk
// recurrence. Stores carry-in state per chunk. grid 32*4=128, block 256, 4 floats/thread
__global__ void __launch_bounds__(256) k_combine(
    const float* __restrict__ G, const float* __restrict__ dec, float* __restrict__ Hin) {
  int bh = blockIdx.x >> 2, esp = blockIdx.x & 3;
  int e = esp*1024 + threadIdx.x*4;
  size_t base0 = (size_t)bh*NCH*4096 + e;
  float4 H = make_float4(0.f,0.f,0.f,0.f);
  float4 g = *(const float4*)(G + base0);
  float d = dec[bh*NCH];
  for (int c = 0; c < NCH; ++c) {
    float4 gn = make_float4(0.f,0.f,0.f,0.f); float dn = 0.f;
    if (c + 1 < NCH) {
      gn = *(const float4*)(G + base0 + (size_t)(c+1)*4096);
      dn = dec[bh*NCH + c + 1];
    }
    *(float4*)(Hin + base0 + (size_t)c*4096) = H;   // carry-in for chunk c
    H.x = H.x*d + g.x; H.y = H.y*d + g.y; H.z = H.z*d + g.z; H.w = H.w*d + g.w;
    g = gn; d = dn;
  }
}

// ---------------------------------------------------------------- phase C: chunk output
// y[t][p] = sum_{s<=t} exp(A(cum_t-cum_s))dt_s (C_t.B_s) x_s[p] + exp(A cum_t) C_t.H_in[p,:]
// grid 1024, block 256. Tiles: t = tr+16j (tr=tid>>4), p = tc*4..+3 (tc=tid&15), s' = tc+16i
__global__ void __launch_bounds__(256) k_chunk_out(
    const float* __restrict__ zx, const float* __restrict__ xbc,
    const float* __restrict__ A_log, const float* __restrict__ Hin,
    float* __restrict__ y) {
  int blk = blockIdx.x;
  int c = blk & (NCH-1), hd = (blk >> 5) & 3, b = blk >> 7;
  int t0 = c*QC;
  int tid = threadIdx.x;
  int tr = tid >> 4, tc = tid & 15;
  float A = -__expf(A_log[hd]);
  __shared__ __align__(16) float SA[QC*LDP];   // B, then X
  __shared__ __align__(16) float SB[QC*LDP];   // C
  __shared__ __align__(16) float SC[QC*LDP];   // M, then HT
  __shared__ float cum[QC], dts[QC], pref[QC];
  if (tid < 64) {
    int tg = t0 + tid;
    float dtv = (tg < LH) ? zx[((size_t)b*LH + tg)*DPROJ + 640 + hd] : 0.f;
    float s = dtv;
#pragma unroll
    for (int off = 1; off < 64; off <<= 1) {
      float u = __shfl_up(s, off);
      if (tid >= off) s += u;
    }
    dts[tid] = dtv; cum[tid] = s; pref[tid] = __expf(A*s);
  }
  for (int i = tid; i < QC*64; i += 256) {
    int s = i >> 6, j = i & 63;
    int tg = t0 + s;
    float bv = 0.f, cv = 0.f;
    if (tg < LH) {
      size_t row = ((size_t)b*LH + tg)*CONVD;
      bv = xbc[row + DIN + j];
      cv = xbc[row + DIN + NSTATE + j];
    }
    SA[s*LDP + j] = bv; SB[s*LDP + j] = cv;
  }
  __syncthreads();
  // ---- S = C B^T  (tile: t = tr+16j, s' = tc+16i)
  float S[4][4];
#pragma unroll
  for (int j = 0; j < 4; ++j)
#pragma unroll
    for (int i = 0; i < 4; ++i) S[j][i] = 0.f;
  const float4* SA4 = (const float4*)SA;
  const float4* SB4 = (const float4*)SB;
  for (int n4 = 0; n4 < 16; ++n4) {
    float4 cv[4], bv[4];
#pragma unroll
    for (int j = 0; j < 4; ++j) cv[j] = SB4[(tr + 16*j)*(LDP/4) + n4];
#pragma unroll
    for (int i = 0; i < 4; ++i) bv[i] = SA4[(tc + 16*i)*(LDP/4) + n4];
#pragma unroll
    for (int j = 0; j < 4; ++j)
#pragma unroll
      for (int i = 0; i < 4; ++i)
        S[j][i] += cv[j].x*bv[i].x + cv[j].y*bv[i].y + cv[j].z*bv[i].z + cv[j].w*bv[i].w;
  }
  __syncthreads();
  // ---- masked decay -> M in SC; reload X into SA
#pragma unroll
  for (int j = 0; j < 4; ++j) {
    int t = tr + 16*j;
#pragma unroll
    for (int i = 0; i < 4; ++i) {
      int s = tc + 16*i;
      float m = 0.f;
      if (s <= t) m = S[j][i] * __expf(A*(cum[t] - cum[s])) * dts[s];
      SC[t*LDP + s] = m;
    }
  }
  for (int i = tid; i < QC*64; i += 256) {
    int s = i >> 6, j = i & 63;
    int tg = t0 + s;
    SA[s*LDP + j] = (tg < LH) ? xbc[((size_t)b*LH + tg)*CONVD + hd*PDIM + j] : 0.f;
  }
  __syncthreads();
  // ---- Y1 = M X  (tile: t = tr+16j, p = tc*4..+3)
  float4 y1[4];
#pragma unroll
  for (int j = 0; j < 4; ++j) y1[j] = make_float4(0.f,0.f,0.f,0.f);
  const float4* SC4 = (const float4*)SC;
  for (int s4 = 0; s4 < 16; ++s4) {
    float4 mj[4], xk[4];
#pragma unroll
    for (int j = 0; j < 4; ++j) mj[j] = SC4[(tr + 16*j)*(LDP/4) + s4];
#pragma unroll
    for (int k = 0; k < 4; ++k) xk[k] = SA4[(s4*4 + k)*(LDP/4) + tc];
#pragma unroll
    for (int j = 0; j < 4; ++j) {
      y1[j].x += mj[j].x*xk[0].x + mj[j].y*xk[1].x + mj[j].z*xk[2].x + mj[j].w*xk[3].x;
      y1[j].y += mj[j].x*xk[0].y + mj[j].y*xk[1].y + mj[j].z*xk[2].y + mj[j].w*xk[3].y;
      y1[j].z += mj[j].x*xk[0].z + mj[j].y*xk[1].z + mj[j].z*xk[2].z + mj[j].w*xk[3].z;
      y1[j].w += mj[j].x*xk[0].w + mj[j].y*xk[1].w + mj[j].z*xk[2].w + mj[j].w*xk[3].w;
    }
  }
  __syncthreads();
  // ---- load HT (flat [n*64+p]) into SC
  size_t hbase = (size_t)blk*4096;
  for (int i = tid; i < 4096; i += 256) SC[(i >> 6)*LDP + (i & 63)] = Hin[hbase + i];
  __syncthreads();
  // ---- Y2 = C H_in^T  (reduction over n)
  float4 y2[4];
#pragma unroll
  for (int j = 0; j < 4; ++j) y2[j] = make_float4(0.f,0.f,0.f,0.f);
  for (int n4 = 0; n4 < 16; ++n4) {
    float4 cj[4], hk[4];
#pragma unroll
    for (int j = 0; j < 4; ++j) cj[j] = SB4[(tr + 16*j)*(LDP/4) + n4];
#pragma unroll
    for (int k = 0; k < 4; ++k) hk[k] = SC4[(n4*4 + k)*(LDP/4) + tc];
#pragma unroll
    for (int j = 0; j < 4; ++j) {
      y2[j].x += cj[j].x*hk[0].x + cj[j].y*hk[1].x + cj[j].z*hk[2].x + cj[j].w*hk[3].x;
      y2[j].y += cj[j].x*hk[0].y + cj[j].y*hk[1].y + cj[j].z*hk[2].y + cj[j].w*hk[3].y;
      y2[j].z += cj[j].x*hk[0].z + cj[j].y*hk[1].z + cj[j].z*hk[2].z + cj[j].w*hk[3].z;
      y2[j].w += cj[j].x*hk[0].w + cj[j].y*hk[1].w + cj[j].z*hk[2].w + cj[j].w*hk[3].w;
    }
  }
#pragma unroll
  for (int j = 0; j < 4; ++j) {
    int t = tr + 16*j, tg = t0 + t;
    if (tg < LH) {
      float pr = pref[t];
      float4 o;
      o.x = y1[j].x + pr*y2[j].x;
      o.y = y1[j].y + pr*y2[j].y;
      o.z = y1[j].z + pr*y2[j].z;
      o.w = y1[j].w + pr*y2[j].w;
      *(float4*)(y + ((size_t)b*LH + tg)*DIN + hd*PDIM + tc*4) = o;
    }
  }
}

// ---------------------------------------------------------------- gate + rmsnorm + out_proj
#define TR5 8
__global__ void k_out(const float* __restrict__ y, const float* __restrict__ xbc,
                      const float* __restrict__ zx, const float* __restrict__ Dh,
                      const float* __restrict__ nw, const float* __restrict__ ow,
                      float* __restrict__ h) {
  const int nblk_l = (LH + TR5 - 1) / TR5;    // 256
  int b = blockIdx.x / nblk_l;
  int l0 = (blockIdx.x % nblk_l) * TR5;
  int t = threadIdx.x;
  __shared__ float yv[TR5][DIN];
  __shared__ float red[TR5][4];
  __shared__ float rs[TR5];
  int c = t;
  int hd = c >> 6;
  float dcoef = Dh[hd];
  float nwc = nw[c];
  float v[TR5];
#pragma unroll
  for (int r = 0; r < TR5; ++r) {
    int l = l0 + r;
    float val = 0.f;
    if (l < LH) {
      size_t row = (size_t)b*LH + l;
      float ys = y[row*DIN + c];
      float xh = xbc[row*CONVD + c];
      float z  = zx[row*DPROJ + c];
      val = (ys + dcoef*xh) * siluf_(z);
    }
    v[r] = val;
  }
  int wave = t >> 6, lane = t & 63;
#pragma unroll
  for (int r = 0; r < TR5; ++r) {
    float sq = v[r]*v[r];
    for (int off = 32; off > 0; off >>= 1) sq += __shfl_down(sq, off);
    if (lane == 0) red[r][wave] = sq;
  }
  __syncthreads();
  if (t < TR5) {
    float sm = red[t][0]+red[t][1]+red[t][2]+red[t][3];
    rs[t] = rsqrtf(sm/(float)DIN + 1e-5f);
  }
  __syncthreads();
#pragma unroll
  for (int r = 0; r < TR5; ++r) yv[r][c] = v[r] * rs[r] * nwc;
  __syncthreads();
  int j = t & 127, hf = t >> 7;
  float acc[TR5];
#pragma unroll
  for (int r = 0; r < TR5; ++r) acc[r] = 0.f;
  const float* wr = ow + (size_t)j*DIN + hf*128;
  for (int k = 0; k < 128; ++k) {
    float wv = wr[k];
#pragma unroll
    for (int r = 0; r < TR5; ++r) acc[r] += wv * yv[r][hf*128 + k];
  }
  __syncthreads();
#pragma unroll
  for (int r = 0; r < TR5; ++r) yv[r][hf*128 + j] = acc[r];
  __syncthreads();
  if (hf == 0) {
#pragma unroll
    for (int r = 0; r < TR5; ++r) {
      int l = l0 + r;
      if (l < LH) h[((size_t)b*LH + l)*DIM + j] = yv[r][j] + yv[r][128 + j];
    }
  }
}

// ---------------------------------------------------------------- final LN + head
__global__ void k_head(const float* __restrict__ h, const float* __restrict__ lnw,
                       const float* __restrict__ lnb, const float* __restrict__ hw,
                       const float* __restrict__ hb, float* __restrict__ out) {
  int b = blockIdx.x; int t = threadIdx.x;
  __shared__ float red[2];
  int wave = t >> 6, lane = t & 63;
  float v = h[((size_t)b*LH + LSEQ)*DIM + t];
  float s = v;
  for (int off = 32; off > 0; off >>= 1) s += __shfl_down(s, off);
  if (lane == 0) red[wave] = s;
  __syncthreads();
  float mean = (red[0]+red[1]) / (float)DIM;
  __syncthreads();
  float d = v - mean; float sq = d*d;
  for (int off = 32; off > 0; off >>= 1) sq += __shfl_down(sq, off);
  if (lane == 0) red[wave] = sq;
  __syncthreads();
  float var = (red[0]+red[1]) / (float)DIM;
  float cn = d*rsqrtf(var + 1e-5f)*lnw[t] + lnb[t];
  float dot = cn*hw[t];
  __syncthreads();
  for (int off = 32; off > 0; off >>= 1) dot += __shfl_down(dot, off);
  if (lane == 0) red[wave] = dot;
  __syncthreads();
  if (t == 0) out[b] = red[0]+red[1] + hb[0];
}

// ---------------------------------------------------------------- h -> d_out copy
__global__ void k_copy(const float* __restrict__ src, float* __restrict__ dst, long n4) {
  long i = (long)blockIdx.x*blockDim.x + threadIdx.x;
  if (i < n4) ((float4*)dst)[i] = ((const float4*)src)[i];
}

extern "C" void kernel_launch(void* const* d_in, const int* in_sizes, int n_in,
                              void* d_out, int out_size, void* d_ws, size_t ws_size,
                              hipStream_t stream) {
  const float* x     = (const float*)d_in[0];
  const float* w1    = (const float*)d_in[1];
  const float* b1    = (const float*)d_in[2];
  const float* w2    = (const float*)d_in[3];
  const float* b2    = (const float*)d_in[4];
  const float* cls   = (const float*)d_in[5];
  const float* inw   = (const float*)d_in[6];   // (4, 644, 128)
  const float* cw    = (const float*)d_in[7];   // (4, 384, 4)
  const float* cb    = (const float*)d_in[8];   // (4, 384)
  const float* dtb   = (const float*)d_in[9];   // (4, 4)
  const float* Alog  = (const float*)d_in[10];  // (4, 4)
  const float* Dh    = (const float*)d_in[11];  // (4, 4)
  const float* nw    = (const float*)d_in[12];  // (4, 256)
  const float* ow    = (const float*)d_in[13];  // (4, 128, 256)
  const float* lnw   = (const float*)d_in[14];
  const float* lnb   = (const float*)d_in[15];
  const float* hw    = (const float*)d_in[16];
  const float* hb    = (const float*)d_in[17];

  float* ws   = (float*)d_ws;
  float* hbuf = ws;                                   // 2,094,080
  float* zx   = hbuf + (size_t)BATCH*LH*DIM;          // 10,535,840
  float* xbc  = zx   + (size_t)BATCH*LH*DPROJ;        // 6,282,240
  float* ybuf = xbc  + (size_t)BATCH*LH*CONVD;        // 4,194,304 (G aliases ybuf)
  float* G    = ybuf;                                 //   (consumed before y written)
  float* Hin  = ybuf + 4194304;                       // 4,194,304
  float* dec  = Hin  + 4194304;                       // 1,024
  // total: 27,301,792 floats = 104.2 MiB

  k_front<<<BATCH*LH, 128, 0, stream>>>(x, w1, b1, w2, b2, cls, hbuf);

  for (int i = 0; i < DEPTH; ++i) {
    k_inproj<<<BATCH*((LH+TR2-1)/TR2), 256, 0, stream>>>(
        hbuf, inw + (size_t)i*DPROJ*DIM, dtb + i*NH, zx);
    {
      long total = (long)BATCH*LH*CONVD;
      k_conv<<<(int)((total + 255)/256), 256, 0, stream>>>(
          zx, cw + (size_t)i*CONVD*4, cb + (size_t)i*CONVD, xbc);
    }
    k_chunk_state<<<BATCH*NH*NCH, 256, 0, stream>>>(zx, xbc, Alog + i*NH, G, dec);
    k_combine<<<BATCH*NH*4, 256, 0, stream>>>(G, dec, Hin);
    k_chunk_out<<<BATCH*NH*NCH, 256, 0, stream>>>(zx, xbc, Alog + i*NH, Hin, ybuf);
    k_out<<<BATCH*((LH+TR5-1)/TR5), 256, 0, stream>>>(
        ybuf, xbc, zx, Dh + i*NH, nw + (size_t)i*DIN, ow + (size_t)i*DIM*DIN, hbuf);
  }

  k_head<<<BATCH, 128, 0, stream>>>(hbuf, lnw, lnb, hw, hb, (float*)d_out);
  {
    long n4 = (long)BATCH*LH*DIM/4;
    k_copy<<<(int)((n4 + 255)/256), 256, 0, stream>>>(hbuf, (float*)d_out + 8, n4);
  }
}

// Round 3
// 1132.066 us; speedup vs baseline: 3.7480x; 2.0347x over previous
//
#include <hip/hip_runtime.h>
#include <math.h>

// Shapes (fixed by setup_inputs)
#define BATCH 8
#define TSEQ 2048
#define CIN 3
#define WIN 5
#define LSEQ 2044          // T - WIN + 1
#define LH 2045            // LSEQ + 1 (cls token appended)
#define DIM 128
#define DEPTH 4
#define DIN 256            // d_inner
#define NH 4               // heads
#define PDIM 64            // headdim
#define NSTATE 64          // d_state
#define CONVD 384          // d_inner + 2*d_state
#define DPROJ 644          // 2*d_inner + 2*d_state + nheads
#define QC 64              // chunk length
#define NCH 32             // number of chunks (32*64 = 2048 >= 2045)
#define LDP 68             // padded LDS row stride (17 float4s; bank-spread)

__device__ __forceinline__ float sigmoidf_(float x){ return 1.f/(1.f+__expf(-x)); }
__device__ __forceinline__ float siluf_(float x){ return x*sigmoidf_(x); }

// ---------------------------------------------------------------- front MLP
__global__ void k_front(const float* __restrict__ x, const float* __restrict__ w1,
                        const float* __restrict__ b1, const float* __restrict__ w2,
                        const float* __restrict__ b2, const float* __restrict__ cls,
                        float* __restrict__ h) {
  int blk = blockIdx.x;
  int b = blk / LH, l = blk % LH;
  int t = threadIdx.x;
  if (l == LSEQ) { h[((size_t)b*LH + l)*DIM + t] = cls[t]; return; }
  __shared__ float tok[WIN*CIN];
  __shared__ float h1[DIM];
  if (t < WIN*CIN) tok[t] = x[(size_t)b*TSEQ*CIN + (size_t)l*CIN + t];
  __syncthreads();
  float a = b1[t];
  const float* w1r = w1 + t*(WIN*CIN);
#pragma unroll
  for (int k = 0; k < WIN*CIN; ++k) a += tok[k]*w1r[k];
  float g = 0.5f*a*(1.f + erff(a*0.70710678118654752f));   // exact gelu
  h1[t] = g;
  __syncthreads();
  float o = b2[t];
  const float* w2r = w2 + t*DIM;
  for (int k = 0; k < DIM; ++k) o += h1[k]*w2r[k];
  h[((size_t)b*LH + l)*DIM + t] = o;
}

// ---------------------------------------------------------------- in_proj (+ dt softplus)
#define TR2 16
__global__ void k_inproj(const float* __restrict__ h, const float* __restrict__ w,
                         const float* __restrict__ dtb, float* __restrict__ zx) {
  const int nblk_l = (LH + TR2 - 1) / TR2;   // 128
  int b = blockIdx.x / nblk_l;
  int l0 = (blockIdx.x % nblk_l) * TR2;
  int t = threadIdx.x;
  __shared__ float hs[TR2][DIM];
  for (int i = t; i < TR2*DIM; i += 256) {
    int r = i / DIM, k = i % DIM;
    int l = l0 + r;
    hs[r][k] = (l < LH) ? h[((size_t)b*LH + l)*DIM + k] : 0.f;
  }
  __syncthreads();
  for (int j = t; j < DPROJ; j += 256) {
    float acc[TR2];
#pragma unroll
    for (int r = 0; r < TR2; ++r) acc[r] = 0.f;
    const float* wr = w + (size_t)j*DIM;
    for (int k = 0; k < DIM; ++k) {
      float wv = wr[k];
#pragma unroll
      for (int r = 0; r < TR2; ++r) acc[r] += wv * hs[r][k];
    }
    bool isdt = (j >= 2*DIN + 2*NSTATE);      // j >= 640
    float bias = 0.f;
    if (isdt) bias = dtb[j - 640];
    for (int r = 0; r < TR2; ++r) {
      int l = l0 + r;
      if (l >= LH) break;
      float v = acc[r];
      if (isdt) { v += bias; v = (v > 20.f) ? v : log1pf(__expf(v)); } // softplus
      zx[((size_t)b*LH + l)*DPROJ + j] = v;
    }
  }
}

// ---------------------------------------------------------------- causal dwconv + silu
__global__ void k_conv(const float* __restrict__ zx, const float* __restrict__ cw,
                       const float* __restrict__ cb, float* __restrict__ xbc) {
  size_t idx = (size_t)blockIdx.x*blockDim.x + threadIdx.x;
  const size_t total = (size_t)BATCH*LH*CONVD;
  if (idx >= total) return;
  int c = (int)(idx % CONVD);
  size_t bl = idx / CONVD;
  int l = (int)(bl % LH); int b = (int)(bl / LH);
  float acc = cb[c];
#pragma unroll
  for (int k = 0; k < 4; ++k) {
    int tin = l - 3 + k;
    if (tin >= 0) acc += zx[((size_t)b*LH + tin)*DPROJ + DIN + c] * cw[c*4 + k];
  }
  xbc[idx] = siluf_(acc);
}

// ---------------------------------------------------------------- chunked SSD, phase A:
// per-chunk local state G (stored transposed: flat[n*64+p] = H_local[p][n]) + chunk decay
// grid: BATCH*NH*NCH = 1024, block 256
__global__ void __launch_bounds__(256) k_chunk_state(
    const float* __restrict__ zx, const float* __restrict__ xbc,
    const float* __restrict__ A_log, float* __restrict__ G, float* __restrict__ dec) {
  int blk = blockIdx.x;
  int c = blk & (NCH-1), hd = (blk >> 5) & 3, b = blk >> 7;
  int t0 = c*QC;
  int tid = threadIdx.x;
  float A = -__expf(A_log[hd]);
  __shared__ float xs[QC*PDIM];     // [s][p]
  __shared__ float Bs[QC*NSTATE];   // [s][n]
  __shared__ float coef[QC];
  if (tid < 64) {
    int tg = t0 + tid;
    float dtv = (tg < LH) ? zx[((size_t)b*LH + tg)*DPROJ + 640 + hd] : 0.f;
    float s = dtv;
#pragma unroll
    for (int off = 1; off < 64; off <<= 1) {
      float u = __shfl_up(s, off);
      if (tid >= off) s += u;
    }
    float cq = __shfl(s, 63);
    coef[tid] = __expf(A*(cq - s)) * dtv;
    if (tid == 63) dec[blk] = __expf(A * s);
  }
  for (int i = tid; i < QC*64; i += 256) {
    int s = i >> 6, j = i & 63;
    int tg = t0 + s;
    float xv = 0.f, bv = 0.f;
    if (tg < LH) {
      size_t row = ((size_t)b*LH + tg)*CONVD;
      xv = xbc[row + hd*PDIM + j];
      bv = xbc[row + DIN + j];
    }
    xs[i] = xv; Bs[i] = bv;
  }
  __syncthreads();
  int n = tid >> 2, q = tid & 3;            // thread owns (n, p in [q*16, q*16+16))
  float4 acc[4];
#pragma unroll
  for (int i4 = 0; i4 < 4; ++i4) acc[i4] = make_float4(0.f,0.f,0.f,0.f);
  const float4* xs4 = (const float4*)xs;
#pragma unroll 4
  for (int s = 0; s < QC; ++s) {            // capped unroll: keep VGPRs < spill
    float cb_ = coef[s] * Bs[s*64 + n];
#pragma unroll
    for (int i4 = 0; i4 < 4; ++i4) {
      float4 xv = xs4[s*16 + q*4 + i4];
      acc[i4].x += cb_*xv.x; acc[i4].y += cb_*xv.y;
      acc[i4].z += cb_*xv.z; acc[i4].w += cb_*xv.w;
    }
  }
  float4* gp = (float4*)(G + (size_t)blk*4096 + n*64 + q*16);
#pragma unroll
  for (int i4 = 0; i4 < 4; ++i4) gp[i4] = acc[i4];
}

// ---------------------------------------------------------------- phase B: inter-chunk
// recurrence. Stores carry-in state per chunk. grid 32*4=128, block 256, 4 floats/thread
__global__ void __launch_bounds__(256) k_combine(
    const float* __restrict__ G, const float* __restrict__ dec, float* __restrict__ Hin) {
  int bh = blockIdx.x >> 2, esp = blockIdx.x & 3;
  int e = esp*1024 + threadIdx.x*4;
  size_t base0 = (size_t)bh*NCH*4096 + e;
  float4 H = make_float4(0.f,0.f,0.f,0.f);
  float4 g = *(const float4*)(G + base0);
  float d = dec[bh*NCH];
  for (int c = 0; c < NCH; ++c) {
    float4 gn = make_float4(0.f,0.f,0.f,0.f); float dn = 0.f;
    if (c + 1 < NCH) {
      gn = *(const float4*)(G + base0 + (size_t)(c+1)*4096);
      dn = dec[bh*NCH + c + 1];
    }
    *(float4*)(Hin + base0 + (size_t)c*4096) = H;   // carry-in for chunk c
    H.x = H.x*d + g.x; H.y = H.y*d + g.y; H.z = H.z*d + g.z; H.w = H.w*d + g.w;
    g = gn; d = dn;
  }
}

// ---------------------------------------------------------------- phase C: chunk output
// y[t][p] = sum_{s<=t} exp(A(cum_t-cum_s))dt_s (C_t.B_s) x_s[p] + exp(A cum_t) C_t.H_in[p,:]
// grid 1024, block 256. Tiles: t = tr+16j (tr=tid>>4), p = tc*4..+3 (tc=tid&15), s' = tc+16i
__global__ void __launch_bounds__(256) k_chunk_out(
    const float* __restrict__ zx, const float* __restrict__ xbc,
    const float* __restrict__ A_log, const float* __restrict__ Hin,
    float* __restrict__ y) {
  int blk = blockIdx.x;
  int c = blk & (NCH-1), hd = (blk >> 5) & 3, b = blk >> 7;
  int t0 = c*QC;
  int tid = threadIdx.x;
  int tr = tid >> 4, tc = tid & 15;
  float A = -__expf(A_log[hd]);
  __shared__ __align__(16) float SA[QC*LDP];   // B, then X
  __shared__ __align__(16) float SB[QC*LDP];   // C
  __shared__ __align__(16) float SC[QC*LDP];   // M, then HT
  __shared__ float cum[QC], dts[QC], pref[QC];
  if (tid < 64) {
    int tg = t0 + tid;
    float dtv = (tg < LH) ? zx[((size_t)b*LH + tg)*DPROJ + 640 + hd] : 0.f;
    float s = dtv;
#pragma unroll
    for (int off = 1; off < 64; off <<= 1) {
      float u = __shfl_up(s, off);
      if (tid >= off) s += u;
    }
    dts[tid] = dtv; cum[tid] = s; pref[tid] = __expf(A*s);
  }
  for (int i = tid; i < QC*64; i += 256) {
    int s = i >> 6, j = i & 63;
    int tg = t0 + s;
    float bv = 0.f, cv = 0.f;
    if (tg < LH) {
      size_t row = ((size_t)b*LH + tg)*CONVD;
      bv = xbc[row + DIN + j];
      cv = xbc[row + DIN + NSTATE + j];
    }
    SA[s*LDP + j] = bv; SB[s*LDP + j] = cv;
  }
  __syncthreads();
  // ---- S = C B^T  (tile: t = tr+16j, s' = tc+16i)
  float S[4][4];
#pragma unroll
  for (int j = 0; j < 4; ++j)
#pragma unroll
    for (int i = 0; i < 4; ++i) S[j][i] = 0.f;
  const float4* SA4 = (const float4*)SA;
  const float4* SB4 = (const float4*)SB;
#pragma unroll 2
  for (int n4 = 0; n4 < 16; ++n4) {         // capped unroll: keep VGPRs < spill
    float4 cv[4], bv[4];
#pragma unroll
    for (int j = 0; j < 4; ++j) cv[j] = SB4[(tr + 16*j)*(LDP/4) + n4];
#pragma unroll
    for (int i = 0; i < 4; ++i) bv[i] = SA4[(tc + 16*i)*(LDP/4) + n4];
#pragma unroll
    for (int j = 0; j < 4; ++j)
#pragma unroll
      for (int i = 0; i < 4; ++i)
        S[j][i] += cv[j].x*bv[i].x + cv[j].y*bv[i].y + cv[j].z*bv[i].z + cv[j].w*bv[i].w;
  }
  __syncthreads();
  // ---- masked decay -> M in SC; reload X into SA
#pragma unroll
  for (int j = 0; j < 4; ++j) {
    int t = tr + 16*j;
#pragma unroll
    for (int i = 0; i < 4; ++i) {
      int s = tc + 16*i;
      float m = 0.f;
      if (s <= t) m = S[j][i] * __expf(A*(cum[t] - cum[s])) * dts[s];
      SC[t*LDP + s] = m;
    }
  }
  for (int i = tid; i < QC*64; i += 256) {
    int s = i >> 6, j = i & 63;
    int tg = t0 + s;
    SA[s*LDP + j] = (tg < LH) ? xbc[((size_t)b*LH + tg)*CONVD + hd*PDIM + j] : 0.f;
  }
  __syncthreads();
  // ---- Y1 = M X  (tile: t = tr+16j, p = tc*4..+3)
  float4 y1[4];
#pragma unroll
  for (int j = 0; j < 4; ++j) y1[j] = make_float4(0.f,0.f,0.f,0.f);
  const float4* SC4 = (const float4*)SC;
#pragma unroll 2
  for (int s4 = 0; s4 < 16; ++s4) {         // capped unroll
    float4 mj[4], xk[4];
#pragma unroll
    for (int j = 0; j < 4; ++j) mj[j] = SC4[(tr + 16*j)*(LDP/4) + s4];
#pragma unroll
    for (int k = 0; k < 4; ++k) xk[k] = SA4[(s4*4 + k)*(LDP/4) + tc];
#pragma unroll
    for (int j = 0; j < 4; ++j) {
      y1[j].x += mj[j].x*xk[0].x + mj[j].y*xk[1].x + mj[j].z*xk[2].x + mj[j].w*xk[3].x;
      y1[j].y += mj[j].x*xk[0].y + mj[j].y*xk[1].y + mj[j].z*xk[2].y + mj[j].w*xk[3].y;
      y1[j].z += mj[j].x*xk[0].z + mj[j].y*xk[1].z + mj[j].z*xk[2].z + mj[j].w*xk[3].z;
      y1[j].w += mj[j].x*xk[0].w + mj[j].y*xk[1].w + mj[j].z*xk[2].w + mj[j].w*xk[3].w;
    }
  }
  __syncthreads();
  // ---- load HT (flat [n*64+p]) into SC
  size_t hbase = (size_t)blk*4096;
  for (int i = tid; i < 4096; i += 256) SC[(i >> 6)*LDP + (i & 63)] = Hin[hbase + i];
  __syncthreads();
  // ---- Y2 = C H_in^T  (reduction over n)
  float4 y2[4];
#pragma unroll
  for (int j = 0; j < 4; ++j) y2[j] = make_float4(0.f,0.f,0.f,0.f);
#pragma unroll 2
  for (int n4 = 0; n4 < 16; ++n4) {         // capped unroll
    float4 cj[4], hk[4];
#pragma unroll
    for (int j = 0; j < 4; ++j) cj[j] = SB4[(tr + 16*j)*(LDP/4) + n4];
#pragma unroll
    for (int k = 0; k < 4; ++k) hk[k] = SC4[(n4*4 + k)*(LDP/4) + tc];
#pragma unroll
    for (int j = 0; j < 4; ++j) {
      y2[j].x += cj[j].x*hk[0].x + cj[j].y*hk[1].x + cj[j].z*hk[2].x + cj[j].w*hk[3].x;
      y2[j].y += cj[j].x*hk[0].y + cj[j].y*hk[1].y + cj[j].z*hk[2].y + cj[j].w*hk[3].y;
      y2[j].z += cj[j].x*hk[0].z + cj[j].y*hk[1].z + cj[j].z*hk[2].z + cj[j].w*hk[3].z;
      y2[j].w += cj[j].x*hk[0].w + cj[j].y*hk[1].w + cj[j].z*hk[2].w + cj[j].w*hk[3].w;
    }
  }
#pragma unroll
  for (int j = 0; j < 4; ++j) {
    int t = tr + 16*j, tg = t0 + t;
    if (tg < LH) {
      float pr = pref[t];
      float4 o;
      o.x = y1[j].x + pr*y2[j].x;
      o.y = y1[j].y + pr*y2[j].y;
      o.z = y1[j].z + pr*y2[j].z;
      o.w = y1[j].w + pr*y2[j].w;
      *(float4*)(y + ((size_t)b*LH + tg)*DIN + hd*PDIM + tc*4) = o;
    }
  }
}

// ---------------------------------------------------------------- gate + rmsnorm + out_proj
#define TR5 8
__global__ void k_out(const float* __restrict__ y, const float* __restrict__ xbc,
                      const float* __restrict__ zx, const float* __restrict__ Dh,
                      const float* __restrict__ nw, const float* __restrict__ ow,
                      float* __restrict__ h) {
  const int nblk_l = (LH + TR5 - 1) / TR5;    // 256
  int b = blockIdx.x / nblk_l;
  int l0 = (blockIdx.x % nblk_l) * TR5;
  int t = threadIdx.x;
  __shared__ float yv[TR5][DIN];
  __shared__ float red[TR5][4];
  __shared__ float rs[TR5];
  int c = t;
  int hd = c >> 6;
  float dcoef = Dh[hd];
  float nwc = nw[c];
  float v[TR5];
#pragma unroll
  for (int r = 0; r < TR5; ++r) {
    int l = l0 + r;
    float val = 0.f;
    if (l < LH) {
      size_t row = (size_t)b*LH + l;
      float ys = y[row*DIN + c];
      float xh = xbc[row*CONVD + c];
      float z  = zx[row*DPROJ + c];
      val = (ys + dcoef*xh) * siluf_(z);
    }
    v[r] = val;
  }
  int wave = t >> 6, lane = t & 63;
#pragma unroll
  for (int r = 0; r < TR5; ++r) {
    float sq = v[r]*v[r];
    for (int off = 32; off > 0; off >>= 1) sq += __shfl_down(sq, off);
    if (lane == 0) red[r][wave] = sq;
  }
  __syncthreads();
  if (t < TR5) {
    float sm = red[t][0]+red[t][1]+red[t][2]+red[t][3];
    rs[t] = rsqrtf(sm/(float)DIN + 1e-5f);
  }
  __syncthreads();
#pragma unroll
  for (int r = 0; r < TR5; ++r) yv[r][c] = v[r] * rs[r] * nwc;
  __syncthreads();
  int j = t & 127, hf = t >> 7;
  float acc[TR5];
#pragma unroll
  for (int r = 0; r < TR5; ++r) acc[r] = 0.f;
  const float* wr = ow + (size_t)j*DIN + hf*128;
  for (int k = 0; k < 128; ++k) {
    float wv = wr[k];
#pragma unroll
    for (int r = 0; r < TR5; ++r) acc[r] += wv * yv[r][hf*128 + k];
  }
  __syncthreads();
#pragma unroll
  for (int r = 0; r < TR5; ++r) yv[r][hf*128 + j] = acc[r];
  __syncthreads();
  if (hf == 0) {
#pragma unroll
    for (int r = 0; r < TR5; ++r) {
      int l = l0 + r;
      if (l < LH) h[((size_t)b*LH + l)*DIM + j] = yv[r][j] + yv[r][128 + j];
    }
  }
}

// ---------------------------------------------------------------- final LN + head
__global__ void k_head(const float* __restrict__ h, const float* __restrict__ lnw,
                       const float* __restrict__ lnb, const float* __restrict__ hw,
                       const float* __restrict__ hb, float* __restrict__ out) {
  int b = blockIdx.x; int t = threadIdx.x;
  __shared__ float red[2];
  int wave = t >> 6, lane = t & 63;
  float v = h[((size_t)b*LH + LSEQ)*DIM + t];
  float s = v;
  for (int off = 32; off > 0; off >>= 1) s += __shfl_down(s, off);
  if (lane == 0) red[wave] = s;
  __syncthreads();
  float mean = (red[0]+red[1]) / (float)DIM;
  __syncthreads();
  float d = v - mean; float sq = d*d;
  for (int off = 32; off > 0; off >>= 1) sq += __shfl_down(sq, off);
  if (lane == 0) red[wave] = sq;
  __syncthreads();
  float var = (red[0]+red[1]) / (float)DIM;
  float cn = d*rsqrtf(var + 1e-5f)*lnw[t] + lnb[t];
  float dot = cn*hw[t];
  __syncthreads();
  for (int off = 32; off > 0; off >>= 1) dot += __shfl_down(dot, off);
  if (lane == 0) red[wave] = dot;
  __syncthreads();
  if (t == 0) out[b] = red[0]+red[1] + hb[0];
}

// ---------------------------------------------------------------- h -> d_out copy
__global__ void k_copy(const float* __restrict__ src, float* __restrict__ dst, long n4) {
  long i = (long)blockIdx.x*blockDim.x + threadIdx.x;
  if (i < n4) ((float4*)dst)[i] = ((const float4*)src)[i];
}

extern "C" void kernel_launch(void* const* d_in, const int* in_sizes, int n_in,
                              void* d_out, int out_size, void* d_ws, size_t ws_size,
                              hipStream_t stream) {
  const float* x     = (const float*)d_in[0];
  const float* w1    = (const float*)d_in[1];
  const float* b1    = (const float*)d_in[2];
  const float* w2    = (const float*)d_in[3];
  const float* b2    = (const float*)d_in[4];
  const float* cls   = (const float*)d_in[5];
  const float* inw   = (const float*)d_in[6];   // (4, 644, 128)
  const float* cw    = (const float*)d_in[7];   // (4, 384, 4)
  const float* cb    = (const float*)d_in[8];   // (4, 384)
  const float* dtb   = (const float*)d_in[9];   // (4, 4)
  const float* Alog  = (const float*)d_in[10];  // (4, 4)
  const float* Dh    = (const float*)d_in[11];  // (4, 4)
  const float* nw    = (const float*)d_in[12];  // (4, 256)
  const float* ow    = (const float*)d_in[13];  // (4, 128, 256)
  const float* lnw   = (const float*)d_in[14];
  const float* lnb   = (const float*)d_in[15];
  const float* hw    = (const float*)d_in[16];
  const float* hb    = (const float*)d_in[17];

  float* ws   = (float*)d_ws;
  float* hbuf = ws;                                   // 2,094,080
  float* zx   = hbuf + (size_t)BATCH*LH*DIM;          // 10,535,840
  float* xbc  = zx   + (size_t)BATCH*LH*DPROJ;        // 6,282,240
  float* ybuf = xbc  + (size_t)BATCH*LH*CONVD;        // 4,194,304 (G aliases ybuf)
  float* G    = ybuf;                                 //   (consumed before y written)
  float* Hin  = ybuf + 4194304;                       // 4,194,304
  float* dec  = Hin  + 4194304;                       // 1,024
  // total: 27,301,792 floats = 104.2 MiB

  k_front<<<BATCH*LH, 128, 0, stream>>>(x, w1, b1, w2, b2, cls, hbuf);

  for (int i = 0; i < DEPTH; ++i) {
    k_inproj<<<BATCH*((LH+TR2-1)/TR2), 256, 0, stream>>>(
        hbuf, inw + (size_t)i*DPROJ*DIM, dtb + i*NH, zx);
    {
      long total = (long)BATCH*LH*CONVD;
      k_conv<<<(int)((total + 255)/256), 256, 0, stream>>>(
          zx, cw + (size_t)i*CONVD*4, cb + (size_t)i*CONVD, xbc);
    }
    k_chunk_state<<<BATCH*NH*NCH, 256, 0, stream>>>(zx, xbc, Alog + i*NH, G, dec);
    k_combine<<<BATCH*NH*4, 256, 0, stream>>>(G, dec, Hin);
    k_chunk_out<<<BATCH*NH*NCH, 256, 0, stream>>>(zx, xbc, Alog + i*NH, Hin, ybuf);
    k_out<<<BATCH*((LH+TR5-1)/TR5), 256, 0, stream>>>(
        ybuf, xbc, zx, Dh + i*NH, nw + (size_t)i*DIN, ow + (size_t)i*DIM*DIN, hbuf);
  }

  k_head<<<BATCH, 128, 0, stream>>>(hbuf, lnw, lnb, hw, hb, (float*)d_out);
  {
    long n4 = (long)BATCH*LH*DIM/4;
    k_copy<<<(int)((n4 + 255)/256), 256, 0, stream>>>(hbuf, (float*)d_out + 8, n4);
  }
}

// Round 4
// 1031.664 us; speedup vs baseline: 4.1128x; 1.0973x over previous
//
#include <hip/hip_runtime.h>
#include <math.h>

// Shapes (fixed by setup_inputs)
#define BATCH 8
#define TSEQ 2048
#define CIN 3
#define WIN 5
#define LSEQ 2044          // T - WIN + 1
#define LH 2045            // LSEQ + 1 (cls token appended)
#define DIM 128
#define DEPTH 4
#define DIN 256            // d_inner
#define NH 4               // heads
#define PDIM 64            // headdim
#define NSTATE 64          // d_state
#define CONVD 384          // d_inner + 2*d_state
#define DPROJ 644          // 2*d_inner + 2*d_state + nheads
#define QC 64              // chunk length
#define NCH 32             // number of chunks (32*64 = 2048 >= 2045)
#define LDP 68             // padded LDS row stride (17 float4s; bank-spread)
#define FTR 32             // tokens per k_front block

__device__ __forceinline__ float sigmoidf_(float x){ return 1.f/(1.f+__expf(-x)); }
__device__ __forceinline__ float siluf_(float x){ return x*sigmoidf_(x); }

// ---------------------------------------------------------------- front MLP
// grid: BATCH*64 + 1, block 256. 32 tokens/block; w2 half-rows register-cached.
__global__ void __launch_bounds__(256) k_front(
    const float* __restrict__ x, const float* __restrict__ w1,
    const float* __restrict__ b1, const float* __restrict__ w2,
    const float* __restrict__ b2, const float* __restrict__ cls,
    float* __restrict__ h) {
  int t = threadIdx.x;
  if (blockIdx.x == BATCH*64) {              // cls rows
    if (t < DIM) {
      float cv = cls[t];
      for (int b = 0; b < BATCH; ++b) h[((size_t)b*LH + LSEQ)*DIM + t] = cv;
    }
    return;
  }
  int b = blockIdx.x >> 6;
  int c0 = (blockIdx.x & 63) * FTR;
  __shared__ float xs[(FTR+4)*CIN];                  // 108
  __shared__ float w1s[DIM*17];                      // stride 17: 2-way banks = free
  __shared__ __align__(16) float h1s[FTR][DIM];      // 16 KB
  __shared__ float part[FTR][DIM][2];                // 32 KB
  for (int i = t; i < (FTR+4)*CIN; i += 256) {
    int row = c0 + i/3, ch = i - (i/3)*3;
    xs[i] = (row < TSEQ) ? x[(size_t)b*TSEQ*CIN + (size_t)row*CIN + ch] : 0.f;
  }
  for (int i = t; i < DIM*15; i += 256) {
    int j = i/15, k = i - j*15;
    w1s[j*17+k] = w1[i];
  }
  __syncthreads();
  {
    int j = t & 127, rh = t >> 7;
    float bias = b1[j];
    const float* wr = &w1s[j*17];
    for (int r = rh*16; r < rh*16+16; ++r) {
      float a = bias;
#pragma unroll
      for (int k = 0; k < 15; ++k) a += xs[r*3+k]*wr[k];
      h1s[r][j] = 0.5f*a*(1.f + erff(a*0.70710678118654752f));  // exact gelu
    }
  }
  __syncthreads();
  {
    int j = t & 127, hf = t >> 7;
    float4 wv[16];                                   // 64-float w2 half-row in regs
    const float4* w2r = (const float4*)(w2 + (size_t)j*DIM + hf*64);
#pragma unroll
    for (int k4 = 0; k4 < 16; ++k4) wv[k4] = w2r[k4];
#pragma unroll 2
    for (int r = 0; r < FTR; ++r) {
      const float4* hr = (const float4*)&h1s[r][hf*64];
      float acc = 0.f;
#pragma unroll
      for (int k4 = 0; k4 < 16; ++k4) {
        float4 hv = hr[k4];                          // broadcast read: free
        acc += wv[k4].x*hv.x + wv[k4].y*hv.y + wv[k4].z*hv.z + wv[k4].w*hv.w;
      }
      part[r][j][hf] = acc;
    }
  }
  __syncthreads();
  if (t < DIM) {
    float bias = b2[t];
    for (int r = 0; r < FTR; ++r) {
      int l = c0 + r;
      if (l < LSEQ) h[((size_t)b*LH + l)*DIM + t] = part[r][t][0] + part[r][t][1] + bias;
    }
  }
}

// ---------------------------------------------------------------- in_proj (+ dt softplus)
#define TR2 16
__global__ void k_inproj(const float* __restrict__ h, const float* __restrict__ w,
                         const float* __restrict__ dtb, float* __restrict__ zx) {
  const int nblk_l = (LH + TR2 - 1) / TR2;   // 128
  int b = blockIdx.x / nblk_l;
  int l0 = (blockIdx.x % nblk_l) * TR2;
  int t = threadIdx.x;
  __shared__ __align__(16) float hs[TR2][DIM];
  for (int i = t; i < TR2*DIM; i += 256) {
    int r = i / DIM, k = i % DIM;
    int l = l0 + r;
    hs[r][k] = (l < LH) ? h[((size_t)b*LH + l)*DIM + k] : 0.f;
  }
  __syncthreads();
  for (int j = t; j < DPROJ; j += 256) {
    float acc[TR2];
#pragma unroll
    for (int r = 0; r < TR2; ++r) acc[r] = 0.f;
    const float4* wr4 = (const float4*)(w + (size_t)j*DIM);
#pragma unroll 4
    for (int k4 = 0; k4 < 32; ++k4) {
      float4 wv = wr4[k4];
#pragma unroll
      for (int r = 0; r < TR2; ++r) {
        float4 hv = ((const float4*)&hs[r][0])[k4];  // broadcast
        acc[r] += wv.x*hv.x + wv.y*hv.y + wv.z*hv.z + wv.w*hv.w;
      }
    }
    bool isdt = (j >= 2*DIN + 2*NSTATE);      // j >= 640
    float bias = 0.f;
    if (isdt) bias = dtb[j - 640];
    for (int r = 0; r < TR2; ++r) {
      int l = l0 + r;
      if (l >= LH) break;
      float v = acc[r];
      if (isdt) { v += bias; v = (v > 20.f) ? v : log1pf(__expf(v)); } // softplus
      zx[((size_t)b*LH + l)*DPROJ + j] = v;
    }
  }
}

// ---------------------------------------------------------------- causal dwconv + silu
__global__ void k_conv(const float* __restrict__ zx, const float* __restrict__ cw,
                       const float* __restrict__ cb, float* __restrict__ xbc) {
  size_t idx = (size_t)blockIdx.x*blockDim.x + threadIdx.x;
  const size_t total = (size_t)BATCH*LH*CONVD;
  if (idx >= total) return;
  int c = (int)(idx % CONVD);
  size_t bl = idx / CONVD;
  int l = (int)(bl % LH); int b = (int)(bl / LH);
  float acc = cb[c];
#pragma unroll
  for (int k = 0; k < 4; ++k) {
    int tin = l - 3 + k;
    if (tin >= 0) acc += zx[((size_t)b*LH + tin)*DPROJ + DIN + c] * cw[c*4 + k];
  }
  xbc[idx] = siluf_(acc);
}

// ---------------------------------------------------------------- chunked SSD, phase A:
// per-chunk local state G (stored transposed: flat[n*64+p] = H_local[p][n]) + chunk decay
// grid: BATCH*NH*NCH = 1024, block 256
__global__ void __launch_bounds__(256) k_chunk_state(
    const float* __restrict__ zx, const float* __restrict__ xbc,
    const float* __restrict__ A_log, float* __restrict__ G, float* __restrict__ dec) {
  int blk = blockIdx.x;
  int c = blk & (NCH-1), hd = (blk >> 5) & 3, b = blk >> 7;
  int t0 = c*QC;
  int tid = threadIdx.x;
  float A = -__expf(A_log[hd]);
  __shared__ float xs[QC*PDIM];     // [s][p]
  __shared__ float Bs[QC*NSTATE];   // [s][n]
  __shared__ float coef[QC];
  if (tid < 64) {
    int tg = t0 + tid;
    float dtv = (tg < LH) ? zx[((size_t)b*LH + tg)*DPROJ + 640 + hd] : 0.f;
    float s = dtv;
#pragma unroll
    for (int off = 1; off < 64; off <<= 1) {
      float u = __shfl_up(s, off);
      if (tid >= off) s += u;
    }
    float cq = __shfl(s, 63);
    coef[tid] = __expf(A*(cq - s)) * dtv;
    if (tid == 63) dec[blk] = __expf(A * s);
  }
  for (int i = tid; i < QC*64; i += 256) {
    int s = i >> 6, j = i & 63;
    int tg = t0 + s;
    float xv = 0.f, bv = 0.f;
    if (tg < LH) {
      size_t row = ((size_t)b*LH + tg)*CONVD;
      xv = xbc[row + hd*PDIM + j];
      bv = xbc[row + DIN + j];
    }
    xs[i] = xv; Bs[i] = bv;
  }
  __syncthreads();
  int n = tid >> 2, q = tid & 3;            // thread owns (n, p in [q*16, q*16+16))
  float4 acc[4];
#pragma unroll
  for (int i4 = 0; i4 < 4; ++i4) acc[i4] = make_float4(0.f,0.f,0.f,0.f);
  const float4* xs4 = (const float4*)xs;
#pragma unroll 4
  for (int s = 0; s < QC; ++s) {            // capped unroll: keep VGPRs < spill
    float cb_ = coef[s] * Bs[s*64 + n];
#pragma unroll
    for (int i4 = 0; i4 < 4; ++i4) {
      float4 xv = xs4[s*16 + q*4 + i4];
      acc[i4].x += cb_*xv.x; acc[i4].y += cb_*xv.y;
      acc[i4].z += cb_*xv.z; acc[i4].w += cb_*xv.w;
    }
  }
  float4* gp = (float4*)(G + (size_t)blk*4096 + n*64 + q*16);
#pragma unroll
  for (int i4 = 0; i4 < 4; ++i4) gp[i4] = acc[i4];
}

// ---------------------------------------------------------------- phase B: inter-chunk
// recurrence. Stores carry-in state per chunk. grid 32*4=128, block 256, 4 floats/thread
__global__ void __launch_bounds__(256) k_combine(
    const float* __restrict__ G, const float* __restrict__ dec, float* __restrict__ Hin) {
  int bh = blockIdx.x >> 2, esp = blockIdx.x & 3;
  int e = esp*1024 + threadIdx.x*4;
  size_t base0 = (size_t)bh*NCH*4096 + e;
  float4 H = make_float4(0.f,0.f,0.f,0.f);
  float4 g = *(const float4*)(G + base0);
  float d = dec[bh*NCH];
  for (int c = 0; c < NCH; ++c) {
    float4 gn = make_float4(0.f,0.f,0.f,0.f); float dn = 0.f;
    if (c + 1 < NCH) {
      gn = *(const float4*)(G + base0 + (size_t)(c+1)*4096);
      dn = dec[bh*NCH + c + 1];
    }
    *(float4*)(Hin + base0 + (size_t)c*4096) = H;   // carry-in for chunk c
    H.x = H.x*d + g.x; H.y = H.y*d + g.y; H.z = H.z*d + g.z; H.w = H.w*d + g.w;
    g = gn; d = dn;
  }
}

// ---------------------------------------------------------------- phase C: chunk output
// y[t][p] = sum_{s<=t} exp(A(cum_t-cum_s))dt_s (C_t.B_s) x_s[p] + exp(A cum_t) C_t.H_in[p,:]
// grid 1024, block 256. Tiles: t = tr+16j (tr=tid>>4), p = tc*4..+3 (tc=tid&15), s' = tc+16i
__global__ void __launch_bounds__(256) k_chunk_out(
    const float* __restrict__ zx, const float* __restrict__ xbc,
    const float* __restrict__ A_log, const float* __restrict__ Hin,
    float* __restrict__ y) {
  int blk = blockIdx.x;
  int c = blk & (NCH-1), hd = (blk >> 5) & 3, b = blk >> 7;
  int t0 = c*QC;
  int tid = threadIdx.x;
  int tr = tid >> 4, tc = tid & 15;
  float A = -__expf(A_log[hd]);
  __shared__ __align__(16) float SA[QC*LDP];   // B, then X
  __shared__ __align__(16) float SB[QC*LDP];   // C
  __shared__ __align__(16) float SC[QC*LDP];   // M, then HT
  __shared__ float cum[QC], dts[QC], pref[QC];
  if (tid < 64) {
    int tg = t0 + tid;
    float dtv = (tg < LH) ? zx[((size_t)b*LH + tg)*DPROJ + 640 + hd] : 0.f;
    float s = dtv;
#pragma unroll
    for (int off = 1; off < 64; off <<= 1) {
      float u = __shfl_up(s, off);
      if (tid >= off) s += u;
    }
    dts[tid] = dtv; cum[tid] = s; pref[tid] = __expf(A*s);
  }
  for (int i = tid; i < QC*64; i += 256) {
    int s = i >> 6, j = i & 63;
    int tg = t0 + s;
    float bv = 0.f, cv = 0.f;
    if (tg < LH) {
      size_t row = ((size_t)b*LH + tg)*CONVD;
      bv = xbc[row + DIN + j];
      cv = xbc[row + DIN + NSTATE + j];
    }
    SA[s*LDP + j] = bv; SB[s*LDP + j] = cv;
  }
  __syncthreads();
  // ---- S = C B^T  (tile: t = tr+16j, s' = tc+16i)
  float S[4][4];
#pragma unroll
  for (int j = 0; j < 4; ++j)
#pragma unroll
    for (int i = 0; i < 4; ++i) S[j][i] = 0.f;
  const float4* SA4 = (const float4*)SA;
  const float4* SB4 = (const float4*)SB;
#pragma unroll 2
  for (int n4 = 0; n4 < 16; ++n4) {         // capped unroll: keep VGPRs < spill
    float4 cv[4], bv[4];
#pragma unroll
    for (int j = 0; j < 4; ++j) cv[j] = SB4[(tr + 16*j)*(LDP/4) + n4];
#pragma unroll
    for (int i = 0; i < 4; ++i) bv[i] = SA4[(tc + 16*i)*(LDP/4) + n4];
#pragma unroll
    for (int j = 0; j < 4; ++j)
#pragma unroll
      for (int i = 0; i < 4; ++i)
        S[j][i] += cv[j].x*bv[i].x + cv[j].y*bv[i].y + cv[j].z*bv[i].z + cv[j].w*bv[i].w;
  }
  __syncthreads();
  // ---- masked decay -> M in SC; reload X into SA
#pragma unroll
  for (int j = 0; j < 4; ++j) {
    int t = tr + 16*j;
#pragma unroll
    for (int i = 0; i < 4; ++i) {
      int s = tc + 16*i;
      float m = 0.f;
      if (s <= t) m = S[j][i] * __expf(A*(cum[t] - cum[s])) * dts[s];
      SC[t*LDP + s] = m;
    }
  }
  for (int i = tid; i < QC*64; i += 256) {
    int s = i >> 6, j = i & 63;
    int tg = t0 + s;
    SA[s*LDP + j] = (tg < LH) ? xbc[((size_t)b*LH + tg)*CONVD + hd*PDIM + j] : 0.f;
  }
  __syncthreads();
  // ---- Y1 = M X  (tile: t = tr+16j, p = tc*4..+3)
  float4 y1[4];
#pragma unroll
  for (int j = 0; j < 4; ++j) y1[j] = make_float4(0.f,0.f,0.f,0.f);
  const float4* SC4 = (const float4*)SC;
#pragma unroll 2
  for (int s4 = 0; s4 < 16; ++s4) {         // capped unroll
    float4 mj[4], xk[4];
#pragma unroll
    for (int j = 0; j < 4; ++j) mj[j] = SC4[(tr + 16*j)*(LDP/4) + s4];
#pragma unroll
    for (int k = 0; k < 4; ++k) xk[k] = SA4[(s4*4 + k)*(LDP/4) + tc];
#pragma unroll
    for (int j = 0; j < 4; ++j) {
      y1[j].x += mj[j].x*xk[0].x + mj[j].y*xk[1].x + mj[j].z*xk[2].x + mj[j].w*xk[3].x;
      y1[j].y += mj[j].x*xk[0].y + mj[j].y*xk[1].y + mj[j].z*xk[2].y + mj[j].w*xk[3].y;
      y1[j].z += mj[j].x*xk[0].z + mj[j].y*xk[1].z + mj[j].z*xk[2].z + mj[j].w*xk[3].z;
      y1[j].w += mj[j].x*xk[0].w + mj[j].y*xk[1].w + mj[j].z*xk[2].w + mj[j].w*xk[3].w;
    }
  }
  __syncthreads();
  // ---- load HT (flat [n*64+p]) into SC
  size_t hbase = (size_t)blk*4096;
  for (int i = tid; i < 4096; i += 256) SC[(i >> 6)*LDP + (i & 63)] = Hin[hbase + i];
  __syncthreads();
  // ---- Y2 = C H_in^T  (reduction over n)
  float4 y2[4];
#pragma unroll
  for (int j = 0; j < 4; ++j) y2[j] = make_float4(0.f,0.f,0.f,0.f);
#pragma unroll 2
  for (int n4 = 0; n4 < 16; ++n4) {         // capped unroll
    float4 cj[4], hk[4];
#pragma unroll
    for (int j = 0; j < 4; ++j) cj[j] = SB4[(tr + 16*j)*(LDP/4) + n4];
#pragma unroll
    for (int k = 0; k < 4; ++k) hk[k] = SC4[(n4*4 + k)*(LDP/4) + tc];
#pragma unroll
    for (int j = 0; j < 4; ++j) {
      y2[j].x += cj[j].x*hk[0].x + cj[j].y*hk[1].x + cj[j].z*hk[2].x + cj[j].w*hk[3].x;
      y2[j].y += cj[j].x*hk[0].y + cj[j].y*hk[1].y + cj[j].z*hk[2].y + cj[j].w*hk[3].y;
      y2[j].z += cj[j].x*hk[0].z + cj[j].y*hk[1].z + cj[j].z*hk[2].z + cj[j].w*hk[3].z;
      y2[j].w += cj[j].x*hk[0].w + cj[j].y*hk[1].w + cj[j].z*hk[2].w + cj[j].w*hk[3].w;
    }
  }
#pragma unroll
  for (int j = 0; j < 4; ++j) {
    int t = tr + 16*j, tg = t0 + t;
    if (tg < LH) {
      float pr = pref[t];
      float4 o;
      o.x = y1[j].x + pr*y2[j].x;
      o.y = y1[j].y + pr*y2[j].y;
      o.z = y1[j].z + pr*y2[j].z;
      o.w = y1[j].w + pr*y2[j].w;
      *(float4*)(y + ((size_t)b*LH + tg)*DIN + hd*PDIM + tc*4) = o;
    }
  }
}

// ---------------------------------------------------------------- gate + rmsnorm + out_proj
#define TR5 8
__global__ void k_out(const float* __restrict__ y, const float* __restrict__ xbc,
                      const float* __restrict__ zx, const float* __restrict__ Dh,
                      const float* __restrict__ nw, const float* __restrict__ ow,
                      float* __restrict__ h) {
  const int nblk_l = (LH + TR5 - 1) / TR5;    // 256
  int b = blockIdx.x / nblk_l;
  int l0 = (blockIdx.x % nblk_l) * TR5;
  int t = threadIdx.x;
  __shared__ __align__(16) float yv[TR5][DIN];
  __shared__ float red[TR5][4];
  __shared__ float rs[TR5];
  int c = t;
  int hd = c >> 6;
  float dcoef = Dh[hd];
  float nwc = nw[c];
  float v[TR5];
#pragma unroll
  for (int r = 0; r < TR5; ++r) {
    int l = l0 + r;
    float val = 0.f;
    if (l < LH) {
      size_t row = (size_t)b*LH + l;
      float ys = y[row*DIN + c];
      float xh = xbc[row*CONVD + c];
      float z  = zx[row*DPROJ + c];
      val = (ys + dcoef*xh) * siluf_(z);
    }
    v[r] = val;
  }
  int wave = t >> 6, lane = t & 63;
#pragma unroll
  for (int r = 0; r < TR5; ++r) {
    float sq = v[r]*v[r];
    for (int off = 32; off > 0; off >>= 1) sq += __shfl_down(sq, off);
    if (lane == 0) red[r][wave] = sq;
  }
  __syncthreads();
  if (t < TR5) {
    float sm = red[t][0]+red[t][1]+red[t][2]+red[t][3];
    rs[t] = rsqrtf(sm/(float)DIN + 1e-5f);
  }
  __syncthreads();
#pragma unroll
  for (int r = 0; r < TR5; ++r) yv[r][c] = v[r] * rs[r] * nwc;
  __syncthreads();
  int j = t & 127, hf = t >> 7;
  float acc[TR5];
#pragma unroll
  for (int r = 0; r < TR5; ++r) acc[r] = 0.f;
  const float4* wr4 = (const float4*)(ow + (size_t)j*DIN + hf*128);
#pragma unroll 4
  for (int k4 = 0; k4 < 32; ++k4) {
    float4 wv = wr4[k4];
#pragma unroll
    for (int r = 0; r < TR5; ++r) {
      float4 hv = ((const float4*)&yv[r][hf*128])[k4];  // broadcast
      acc[r] += wv.x*hv.x + wv.y*hv.y + wv.z*hv.z + wv.w*hv.w;
    }
  }
  __syncthreads();
#pragma unroll
  for (int r = 0; r < TR5; ++r) yv[r][hf*128 + j] = acc[r];
  __syncthreads();
  if (hf == 0) {
#pragma unroll
    for (int r = 0; r < TR5; ++r) {
      int l = l0 + r;
      if (l < LH) h[((size_t)b*LH + l)*DIM + j] = yv[r][j] + yv[r][128 + j];
    }
  }
}

// ---------------------------------------------------------------- final LN + head
__global__ void k_head(const float* __restrict__ h, const float* __restrict__ lnw,
                       const float* __restrict__ lnb, const float* __restrict__ hw,
                       const float* __restrict__ hb, float* __restrict__ out) {
  int b = blockIdx.x; int t = threadIdx.x;
  __shared__ float red[2];
  int wave = t >> 6, lane = t & 63;
  float v = h[((size_t)b*LH + LSEQ)*DIM + t];
  float s = v;
  for (int off = 32; off > 0; off >>= 1) s += __shfl_down(s, off);
  if (lane == 0) red[wave] = s;
  __syncthreads();
  float mean = (red[0]+red[1]) / (float)DIM;
  __syncthreads();
  float d = v - mean; float sq = d*d;
  for (int off = 32; off > 0; off >>= 1) sq += __shfl_down(sq, off);
  if (lane == 0) red[wave] = sq;
  __syncthreads();
  float var = (red[0]+red[1]) / (float)DIM;
  float cn = d*rsqrtf(var + 1e-5f)*lnw[t] + lnb[t];
  float dot = cn*hw[t];
  __syncthreads();
  for (int off = 32; off > 0; off >>= 1) dot += __shfl_down(dot, off);
  if (lane == 0) red[wave] = dot;
  __syncthreads();
  if (t == 0) out[b] = red[0]+red[1] + hb[0];
}

// ---------------------------------------------------------------- h -> d_out copy
__global__ void k_copy(const float* __restrict__ src, float* __restrict__ dst, long n4) {
  long i = (long)blockIdx.x*blockDim.x + threadIdx.x;
  if (i < n4) ((float4*)dst)[i] = ((const float4*)src)[i];
}

extern "C" void kernel_launch(void* const* d_in, const int* in_sizes, int n_in,
                              void* d_out, int out_size, void* d_ws, size_t ws_size,
                              hipStream_t stream) {
  const float* x     = (const float*)d_in[0];
  const float* w1    = (const float*)d_in[1];
  const float* b1    = (const float*)d_in[2];
  const float* w2    = (const float*)d_in[3];
  const float* b2    = (const float*)d_in[4];
  const float* cls   = (const float*)d_in[5];
  const float* inw   = (const float*)d_in[6];   // (4, 644, 128)
  const float* cw    = (const float*)d_in[7];   // (4, 384, 4)
  const float* cb    = (const float*)d_in[8];   // (4, 384)
  const float* dtb   = (const float*)d_in[9];   // (4, 4)
  const float* Alog  = (const float*)d_in[10];  // (4, 4)
  const float* Dh    = (const float*)d_in[11];  // (4, 4)
  const float* nw    = (const float*)d_in[12];  // (4, 256)
  const float* ow    = (const float*)d_in[13];  // (4, 128, 256)
  const float* lnw   = (const float*)d_in[14];
  const float* lnb   = (const float*)d_in[15];
  const float* hw    = (const float*)d_in[16];
  const float* hb    = (const float*)d_in[17];

  float* ws   = (float*)d_ws;
  float* hbuf = ws;                                   // 2,094,080
  float* zx   = hbuf + (size_t)BATCH*LH*DIM;          // 10,535,840
  float* xbc  = zx   + (size_t)BATCH*LH*DPROJ;        // 6,282,240
  float* ybuf = xbc  + (size_t)BATCH*LH*CONVD;        // 4,194,304 (G aliases ybuf)
  float* G    = ybuf;                                 //   (consumed before y written)
  float* Hin  = ybuf + 4194304;                       // 4,194,304
  float* dec  = Hin  + 4194304;                       // 1,024
  // total: 27,301,792 floats = 104.2 MiB

  k_front<<<BATCH*64 + 1, 256, 0, stream>>>(x, w1, b1, w2, b2, cls, hbuf);

  for (int i = 0; i < DEPTH; ++i) {
    k_inproj<<<BATCH*((LH+TR2-1)/TR2), 256, 0, stream>>>(
        hbuf, inw + (size_t)i*DPROJ*DIM, dtb + i*NH, zx);
    {
      long total = (long)BATCH*LH*CONVD;
      k_conv<<<(int)((total + 255)/256), 256, 0, stream>>>(
          zx, cw + (size_t)i*CONVD*4, cb + (size_t)i*CONVD, xbc);
    }
    k_chunk_state<<<BATCH*NH*NCH, 256, 0, stream>>>(zx, xbc, Alog + i*NH, G, dec);
    k_combine<<<BATCH*NH*4, 256, 0, stream>>>(G, dec, Hin);
    k_chunk_out<<<BATCH*NH*NCH, 256, 0, stream>>>(zx, xbc, Alog + i*NH, Hin, ybuf);
    k_out<<<BATCH*((LH+TR5-1)/TR5), 256, 0, stream>>>(
        ybuf, xbc, zx, Dh + i*NH, nw + (size_t)i*DIN, ow + (size_t)i*DIM*DIN, hbuf);
  }

  k_head<<<BATCH, 128, 0, stream>>>(hbuf, lnw, lnb, hw, hb, (float*)d_out);
  {
    long n4 = (long)BATCH*LH*DIM/4;
    k_copy<<<(int)((n4 + 255)/256), 256, 0, stream>>>(hbuf, (float*)d_out + 8, n4);
  }
}